// Round 4
// baseline (255.920 us; speedup 1.0000x reference)
//
#include <hip/hip_runtime.h>

// Trilerp of 3 feature levels + mesh concat, with SPATIAL COUNTING-SORT.
//
// Rounds 0-3 established: per-wave scheduling is irrelevant (compiler-
// serialized, barrier-hinted, and forced-asm MLP schedules all give 81 us).
// The kernel is congestion-bound: compulsory gather traffic (~717 MB of
// 64-128B random sectors) at per-CU outstanding-miss limits with ~random
// access across a 67 MB lvl1 / 16.7 MB lvl2 / 4.2 MB lvl3 footprint.
// Remaining lever: LOCALITY. This revision:
//   1. counting-sorts points by their lvl3 cell (16^3 per batch, 8192 bins,
//      ~24 pts/bucket): bucket-mates share the SAME 8 lvl3 corners (4 KB),
//      2^3 lvl2 cells and a 4^3 lvl1 brick -> gathers become L1/L2 hits.
//   2. bijective XCD-chunked blockIdx swizzle so consecutive (= spatially
//      adjacent) blocks share one XCD's (non-coherent) L2.
// Sort = histogram -> scan -> scatter into a permutation in d_ws
// (8192*4 + P*4 bytes). Falls back to identity order if ws too small.
// Level-specialized waves as before:
//   lvl1 (64^3 x 32ch):  8 lanes/point  -> 8 points/wave
//   lvl2 (32^3 x 64ch): 16 lanes/point  -> 4 points/wave
//   lvl3 (16^3 x128ch): 32 lanes/point  -> 2 points/wave
// Output layout: [B,N,227] = [32 | 64 | 128 | 3 mesh].

typedef float floatx4 __attribute__((ext_vector_type(4)));

__device__ __forceinline__ int point_batch(int p, int N) {
    int b = 0;
    while (p >= N) { p -= N; ++b; }   // B is tiny (2)
    return b;
}

__device__ __forceinline__ int bucket_of(const float* __restrict__ coords,
                                         int p, int N) {
    const float cx = coords[p * 3 + 0];
    const float cy = coords[p * 3 + 1];
    const float cz = coords[p * 3 + 2];
    int bx = (int)(cx * 16.0f); bx = bx < 0 ? 0 : (bx > 15 ? 15 : bx);
    int by = (int)(cy * 16.0f); by = by < 0 ? 0 : (by > 15 ? 15 : by);
    int bz = (int)(cz * 16.0f); bz = bz < 0 ? 0 : (bz > 15 ? 15 : bz);
    // z fastest: matches feature memory layout (z,c contiguous).
    return ((point_batch(p, N) * 16 + bx) * 16 + by) * 16 + bz;
}

__global__ __launch_bounds__(256) void hist_kernel(
    const float* __restrict__ coords, unsigned* __restrict__ bins,
    int N, int P)
{
    const int p = blockIdx.x * 256 + (int)threadIdx.x;
    if (p < P) atomicAdd(&bins[bucket_of(coords, p, N)], 1u);
}

// Exclusive scan of 8192 bins; 1024 threads x 8 bins each.
__global__ __launch_bounds__(1024) void scan_kernel(unsigned* __restrict__ bins)
{
    __shared__ unsigned part[1024];
    const int t = threadIdx.x;
    unsigned loc[8];
    unsigned s = 0;
    for (int i = 0; i < 8; ++i) {
        unsigned v = bins[t * 8 + i];
        loc[i] = s;           // thread-local exclusive prefix
        s += v;
    }
    part[t] = s;
    __syncthreads();
    for (int off = 1; off < 1024; off <<= 1) {
        unsigned v = (t >= off) ? part[t - off] : 0u;
        __syncthreads();
        part[t] += v;
        __syncthreads();
    }
    const unsigned base = (t == 0) ? 0u : part[t - 1];
    for (int i = 0; i < 8; ++i) bins[t * 8 + i] = base + loc[i];
}

__global__ __launch_bounds__(256) void scatter_kernel(
    const float* __restrict__ coords, unsigned* __restrict__ bins,
    unsigned* __restrict__ perm, int N, int P)
{
    const int p = blockIdx.x * 256 + (int)threadIdx.x;
    if (p < P) {
        const unsigned pos = atomicAdd(&bins[bucket_of(coords, p, N)], 1u);
        perm[pos] = (unsigned)p;
    }
}

// D: grid dim; LPP: lanes per point (== C/4); OCB: output channel base.
template<int D, int LPP, int OCB>
__device__ __forceinline__ void do_level(const float* __restrict__ fbase,
                                         const float* __restrict__ coords,
                                         const unsigned* __restrict__ perm,
                                         float* __restrict__ out,
                                         int sBase, int N, int P)
{
    const int tid  = threadIdx.x;
    const int lane = tid & 63;
    const int wv   = tid >> 6;
    const int slot = sBase + wv * (64 / LPP) + (lane / LPP);
    const int c4   = lane & (LPP - 1);
    if (slot >= P) return;
    const int p = perm ? (int)perm[slot] : slot;

    // coords: identical address within each LPP-lane group -> broadcast fetch
    const float cx = coords[p * 3 + 0];
    const float cy = coords[p * 3 + 1];
    const float cz = coords[p * 3 + 2];

    const float scale = (float)D;                    // 0.5^pow * 128 == D
    const float hi    = (float)((double)D - 1.01);   // matches Python

    const float ix = fminf(fmaxf(cx * scale, 0.01f), hi);
    const float iy = fminf(fmaxf(cy * scale, 0.01f), hi);
    const float iz = fminf(fmaxf(cz * scale, 0.01f), hi);

    const float x1f = floorf(ix), x2f = ceilf(ix);
    const float y1f = floorf(iy), y2f = ceilf(iy);
    const float z1f = floorf(iz), z2f = ceilf(iz);
    const int x1 = (int)x1f, x2 = (int)x2f;
    const int y1 = (int)y1f, y2 = (int)y2f;
    const int z1 = (int)z1f, z2 = (int)z2f;

    // Reference weight convention: wx multiplies the x2 (ceil) sample.
    const float wx = ix - x1f, wx2 = x2f - ix;
    const float wy = iy - y1f, wy2 = y2f - iy;
    const float wz = iz - z1f, wz2 = z2f - iz;

    // Byte offsets from the level base pointer (max 67 MB: fits u32).
    const unsigned baseB = (unsigned)point_batch(p, N) * (unsigned)(D * D * D * LPP * 16)
                         + (unsigned)c4 * 16u;
    #define OFFB(X, Y, Z) (baseB + (unsigned)((((X) * D + (Y)) * D + (Z)) * LPP) * 16u)

    floatx4 v111, v211, v121, v221, v112, v212, v122, v222;
    // 8 gathers issued back-to-back, all in flight simultaneously.
    asm volatile("global_load_dwordx4 %0, %1, %2"
                 : "=v"(v111) : "v"(OFFB(x1, y1, z1)), "s"(fbase));
    asm volatile("global_load_dwordx4 %0, %1, %2"
                 : "=v"(v211) : "v"(OFFB(x2, y1, z1)), "s"(fbase));
    asm volatile("global_load_dwordx4 %0, %1, %2"
                 : "=v"(v121) : "v"(OFFB(x1, y2, z1)), "s"(fbase));
    asm volatile("global_load_dwordx4 %0, %1, %2"
                 : "=v"(v221) : "v"(OFFB(x2, y2, z1)), "s"(fbase));
    asm volatile("global_load_dwordx4 %0, %1, %2"
                 : "=v"(v112) : "v"(OFFB(x1, y1, z2)), "s"(fbase));
    asm volatile("global_load_dwordx4 %0, %1, %2"
                 : "=v"(v212) : "v"(OFFB(x2, y1, z2)), "s"(fbase));
    asm volatile("global_load_dwordx4 %0, %1, %2"
                 : "=v"(v122) : "v"(OFFB(x1, y2, z2)), "s"(fbase));
    asm volatile("global_load_dwordx4 %0, %1, %2"
                 : "=v"(v222) : "v"(OFFB(x2, y2, z2)), "s"(fbase));
    #undef OFFB

    asm volatile("s_waitcnt vmcnt(0)");
    __builtin_amdgcn_sched_barrier(0);

    const floatx4 lx1a = v211 * wx + v111 * wx2;
    const floatx4 lx2a = v221 * wx + v121 * wx2;
    const floatx4 ly1  = lx2a * wy + lx1a * wy2;
    const floatx4 lx1b = v212 * wx + v112 * wx2;
    const floatx4 lx2b = v222 * wx + v122 * wx2;
    const floatx4 ly2  = lx2b * wy + lx1b * wy2;
    const floatx4 r    = ly2  * wz + ly1  * wz2;

    float* o = out + p * 227 + OCB + c4 * 4;
    __builtin_nontemporal_store(r.x, o + 0);
    __builtin_nontemporal_store(r.y, o + 1);
    __builtin_nontemporal_store(r.z, o + 2);
    __builtin_nontemporal_store(r.w, o + 3);
}

__global__ __launch_bounds__(256, 8) void trilerp_kernel(
    const float* __restrict__ f1,      // [B,64,64,64,32]
    const float* __restrict__ f2,      // [B,32,32,32,64]
    const float* __restrict__ f3,      // [B,16,16,16,128]
    const float* __restrict__ coords,  // [B,N,3]
    const float* __restrict__ meshf,   // [B,N,3]
    const unsigned* __restrict__ perm, // [P] sorted-slot -> point (or null)
    float* __restrict__ out,           // [B,N,227]
    int N, int P, int nb1, int nb2, int nb3)
{
    // Bijective XCD-chunked swizzle (m204): consecutive logical blocks
    // (= spatially adjacent buckets) share one XCD's L2.
    const int nwg  = (int)gridDim.x;
    const int orig = (int)blockIdx.x;
    const int q = nwg >> 3, r = nwg & 7;
    const int xcd = orig & 7, j = orig >> 3;
    const int blk = (xcd < r ? xcd * (q + 1) : r * (q + 1) + (xcd - r) * q) + j;

    if (blk < nb1) {
        do_level<64, 8, 0>(f1, coords, perm, out, blk * 32, N, P);
    } else if (blk < nb1 + nb2) {
        do_level<32, 16, 32>(f2, coords, perm, out, (blk - nb1) * 16, N, P);
    } else if (blk < nb1 + nb2 + nb3) {
        do_level<16, 32, 96>(f3, coords, perm, out, (blk - nb1 - nb2) * 8, N, P);
    } else {
        // mesh passthrough: one thread per element of [B,N,3]
        const int e = (blk - nb1 - nb2 - nb3) * 256 + (int)threadIdx.x;
        if (e < P * 3) {
            const int p = e / 3, c = e - p * 3;
            __builtin_nontemporal_store(meshf[e], &out[p * 227 + 224 + c]);
        }
    }
}

extern "C" void kernel_launch(void* const* d_in, const int* in_sizes, int n_in,
                              void* d_out, int out_size, void* d_ws, size_t ws_size,
                              hipStream_t stream) {
    const float* f1     = (const float*)d_in[1];
    const float* f2     = (const float*)d_in[2];
    const float* f3     = (const float*)d_in[3];
    const float* coords = (const float*)d_in[5];
    const float* meshf  = (const float*)d_in[6];
    float* out = (float*)d_out;

    const int B = in_sizes[1] / (64 * 64 * 64 * 32);
    const int N = in_sizes[5] / (B * 3);
    const int P = B * N;

    const int NBINS = 8192;                 // 2 batches x 16^3 cells
    const size_t ws_need = (size_t)NBINS * 4 + (size_t)P * 4;
    unsigned* bins = (unsigned*)d_ws;
    unsigned* perm = bins + NBINS;
    const bool do_sort = (d_ws != nullptr) && (ws_size >= ws_need);

    if (do_sort) {
        hipMemsetAsync(bins, 0, NBINS * 4, stream);
        const int nbp = (P + 255) / 256;
        hist_kernel<<<dim3(nbp), dim3(256), 0, stream>>>(coords, bins, N, P);
        scan_kernel<<<dim3(1), dim3(1024), 0, stream>>>(bins);
        scatter_kernel<<<dim3(nbp), dim3(256), 0, stream>>>(coords, bins, perm, N, P);
    }

    const int nb1 = (P + 31) / 32;          // 32 points/block (8 pts/wave)
    const int nb2 = (P + 15) / 16;          // 16 points/block
    const int nb3 = (P + 7) / 8;            //  8 points/block
    const int nbm = (P * 3 + 255) / 256;    // mesh copy blocks
    const int grid = nb1 + nb2 + nb3 + nbm;

    trilerp_kernel<<<dim3(grid), dim3(256), 0, stream>>>(
        f1, f2, f3, coords, meshf, do_sort ? perm : nullptr,
        out, N, P, nb1, nb2, nb3);
}

// Round 5
// 232.775 us; speedup vs baseline: 1.0994x; 1.0994x over previous
//
#include <hip/hip_runtime.h>

// Trilerp of 3 feature levels + mesh concat, with spatial counting-sort.
//
// Round-4 lessons (FETCH 127->42.6 MB proved the sort works; time 81->107 us
// regressed): (a) the GLOBAL XCD-chunked swizzle partitioned the level-
// segmented grid BY LEVEL across XCDs -> XCD0-1 got all of heavy lvl1,
// XCD3-7 the cheap lvl3 => imbalance + drain tail (occupancy 75->46%).
// (b) perm->random-coords->gather made a 3-deep serial latency chain.
// This revision keeps the sort and fixes both:
//   1. bijective chunked XCD swizzle applied PER LEVEL SEGMENT: balanced
//      8-way per level AND spatially-contiguous chunk per XCD L2.
//   2. scatter materializes SORTED coords (csort) -> trilerp's coord read
//      is a contiguous broadcast (one less random round-trip); perm is only
//      needed for the output row address.
// Level-specialized waves as before:
//   lvl1 (64^3 x 32ch):  8 lanes/point  -> 8 points/wave
//   lvl2 (32^3 x 64ch): 16 lanes/point  -> 4 points/wave
//   lvl3 (16^3 x128ch): 32 lanes/point  -> 2 points/wave
// Output layout: [B,N,227] = [32 | 64 | 128 | 3 mesh].

typedef float floatx4 __attribute__((ext_vector_type(4)));

__device__ __forceinline__ int point_batch(int p, int N) {
    int b = 0;
    while (p >= N) { p -= N; ++b; }   // B is tiny (2)
    return b;
}

__device__ __forceinline__ int bucket_of(const float* __restrict__ coords,
                                         int p, int N) {
    const float cx = coords[p * 3 + 0];
    const float cy = coords[p * 3 + 1];
    const float cz = coords[p * 3 + 2];
    int bx = (int)(cx * 16.0f); bx = bx < 0 ? 0 : (bx > 15 ? 15 : bx);
    int by = (int)(cy * 16.0f); by = by < 0 ? 0 : (by > 15 ? 15 : by);
    int bz = (int)(cz * 16.0f); bz = bz < 0 ? 0 : (bz > 15 ? 15 : bz);
    // z fastest: matches feature memory layout (z,c contiguous).
    return ((point_batch(p, N) * 16 + bx) * 16 + by) * 16 + bz;
}

__global__ __launch_bounds__(256) void hist_kernel(
    const float* __restrict__ coords, unsigned* __restrict__ bins,
    int N, int P)
{
    const int p = blockIdx.x * 256 + (int)threadIdx.x;
    if (p < P) atomicAdd(&bins[bucket_of(coords, p, N)], 1u);
}

// Exclusive scan of 8192 bins; 1024 threads x 8 bins each.
__global__ __launch_bounds__(1024) void scan_kernel(unsigned* __restrict__ bins)
{
    __shared__ unsigned part[1024];
    const int t = threadIdx.x;
    unsigned loc[8];
    unsigned s = 0;
    for (int i = 0; i < 8; ++i) {
        unsigned v = bins[t * 8 + i];
        loc[i] = s;           // thread-local exclusive prefix
        s += v;
    }
    part[t] = s;
    __syncthreads();
    for (int off = 1; off < 1024; off <<= 1) {
        unsigned v = (t >= off) ? part[t - off] : 0u;
        __syncthreads();
        part[t] += v;
        __syncthreads();
    }
    const unsigned base = (t == 0) ? 0u : part[t - 1];
    for (int i = 0; i < 8; ++i) bins[t * 8 + i] = base + loc[i];
}

__global__ __launch_bounds__(256) void scatter_kernel(
    const float* __restrict__ coords, unsigned* __restrict__ bins,
    unsigned* __restrict__ perm, float* __restrict__ csort,
    int N, int P)
{
    const int p = blockIdx.x * 256 + (int)threadIdx.x;
    if (p < P) {
        const unsigned pos = atomicAdd(&bins[bucket_of(coords, p, N)], 1u);
        perm[pos] = (unsigned)p;
        csort[pos * 3 + 0] = coords[p * 3 + 0];
        csort[pos * 3 + 1] = coords[p * 3 + 1];
        csort[pos * 3 + 2] = coords[p * 3 + 2];
    }
}

// Bijective chunked XCD swizzle within a segment of S blocks (m204 variant).
__device__ __forceinline__ int seg_swz(int lo, int S) {
    const int q = S >> 3, r = S & 7;
    const int xcd = lo & 7, j = lo >> 3;
    return (xcd < r ? xcd * (q + 1) : r * (q + 1) + (xcd - r) * q) + j;
}

// D: grid dim; LPP: lanes per point (== C/4); OCB: output channel base.
template<int D, int LPP, int OCB>
__device__ __forceinline__ void do_level(const float* __restrict__ fbase,
                                         const float* __restrict__ coords,
                                         const float* __restrict__ csort,
                                         const unsigned* __restrict__ perm,
                                         float* __restrict__ out,
                                         int sBase, int N, int P)
{
    const int tid  = threadIdx.x;
    const int lane = tid & 63;
    const int wv   = tid >> 6;
    const int slot = sBase + wv * (64 / LPP) + (lane / LPP);
    const int c4   = lane & (LPP - 1);
    if (slot >= P) return;
    const int p = perm ? (int)perm[slot] : slot;   // output row (original order)

    // coords: sorted copy when available -> contiguous broadcast read.
    const float* cp = csort ? (csort + slot * 3) : (coords + p * 3);
    const float cx = cp[0];
    const float cy = cp[1];
    const float cz = cp[2];

    const float scale = (float)D;                    // 0.5^pow * 128 == D
    const float hi    = (float)((double)D - 1.01);   // matches Python

    const float ix = fminf(fmaxf(cx * scale, 0.01f), hi);
    const float iy = fminf(fmaxf(cy * scale, 0.01f), hi);
    const float iz = fminf(fmaxf(cz * scale, 0.01f), hi);

    const float x1f = floorf(ix), x2f = ceilf(ix);
    const float y1f = floorf(iy), y2f = ceilf(iy);
    const float z1f = floorf(iz), z2f = ceilf(iz);
    const int x1 = (int)x1f, x2 = (int)x2f;
    const int y1 = (int)y1f, y2 = (int)y2f;
    const int z1 = (int)z1f, z2 = (int)z2f;

    // Reference weight convention: wx multiplies the x2 (ceil) sample.
    const float wx = ix - x1f, wx2 = x2f - ix;
    const float wy = iy - y1f, wy2 = y2f - iy;
    const float wz = iz - z1f, wz2 = z2f - iz;

    // Byte offsets from the level base pointer (max 67 MB: fits u32).
    const unsigned baseB = (unsigned)point_batch(p, N) * (unsigned)(D * D * D * LPP * 16)
                         + (unsigned)c4 * 16u;
    #define OFFB(X, Y, Z) (baseB + (unsigned)((((X) * D + (Y)) * D + (Z)) * LPP) * 16u)

    floatx4 v111, v211, v121, v221, v112, v212, v122, v222;
    // 8 gathers issued back-to-back, all in flight simultaneously.
    asm volatile("global_load_dwordx4 %0, %1, %2"
                 : "=v"(v111) : "v"(OFFB(x1, y1, z1)), "s"(fbase));
    asm volatile("global_load_dwordx4 %0, %1, %2"
                 : "=v"(v211) : "v"(OFFB(x2, y1, z1)), "s"(fbase));
    asm volatile("global_load_dwordx4 %0, %1, %2"
                 : "=v"(v121) : "v"(OFFB(x1, y2, z1)), "s"(fbase));
    asm volatile("global_load_dwordx4 %0, %1, %2"
                 : "=v"(v221) : "v"(OFFB(x2, y2, z1)), "s"(fbase));
    asm volatile("global_load_dwordx4 %0, %1, %2"
                 : "=v"(v112) : "v"(OFFB(x1, y1, z2)), "s"(fbase));
    asm volatile("global_load_dwordx4 %0, %1, %2"
                 : "=v"(v212) : "v"(OFFB(x2, y1, z2)), "s"(fbase));
    asm volatile("global_load_dwordx4 %0, %1, %2"
                 : "=v"(v122) : "v"(OFFB(x1, y2, z2)), "s"(fbase));
    asm volatile("global_load_dwordx4 %0, %1, %2"
                 : "=v"(v222) : "v"(OFFB(x2, y2, z2)), "s"(fbase));
    #undef OFFB

    asm volatile("s_waitcnt vmcnt(0)");
    __builtin_amdgcn_sched_barrier(0);

    const floatx4 lx1a = v211 * wx + v111 * wx2;
    const floatx4 lx2a = v221 * wx + v121 * wx2;
    const floatx4 ly1  = lx2a * wy + lx1a * wy2;
    const floatx4 lx1b = v212 * wx + v112 * wx2;
    const floatx4 lx2b = v222 * wx + v122 * wx2;
    const floatx4 ly2  = lx2b * wy + lx1b * wy2;
    const floatx4 r    = ly2  * wz + ly1  * wz2;

    float* o = out + p * 227 + OCB + c4 * 4;
    __builtin_nontemporal_store(r.x, o + 0);
    __builtin_nontemporal_store(r.y, o + 1);
    __builtin_nontemporal_store(r.z, o + 2);
    __builtin_nontemporal_store(r.w, o + 3);
}

__global__ __launch_bounds__(256, 8) void trilerp_kernel(
    const float* __restrict__ f1,      // [B,64,64,64,32]
    const float* __restrict__ f2,      // [B,32,32,32,64]
    const float* __restrict__ f3,      // [B,16,16,16,128]
    const float* __restrict__ coords,  // [B,N,3]
    const float* __restrict__ meshf,   // [B,N,3]
    const float* __restrict__ csort,   // [P,3] sorted coords (or null)
    const unsigned* __restrict__ perm, // [P] sorted-slot -> point (or null)
    float* __restrict__ out,           // [B,N,227]
    int N, int P, int nb1, int nb2, int nb3)
{
    // Per-SEGMENT bijective XCD swizzle: balanced across XCDs per level,
    // spatially-contiguous chunk per XCD L2. (Global chunking was the
    // round-4 mistake: it partitioned LEVELS across XCDs.)
    const int orig = (int)blockIdx.x;
    if (orig < nb1) {
        const int blk = seg_swz(orig, nb1);
        do_level<64, 8, 0>(f1, coords, csort, perm, out, blk * 32, N, P);
    } else if (orig < nb1 + nb2) {
        const int blk = seg_swz(orig - nb1, nb2);
        do_level<32, 16, 32>(f2, coords, csort, perm, out, blk * 16, N, P);
    } else if (orig < nb1 + nb2 + nb3) {
        const int blk = seg_swz(orig - nb1 - nb2, nb3);
        do_level<16, 32, 96>(f3, coords, csort, perm, out, blk * 8, N, P);
    } else {
        // mesh passthrough: one thread per element of [B,N,3]; independent
        // of the sort (reads/writes original point order, coalesced).
        const int e = (orig - nb1 - nb2 - nb3) * 256 + (int)threadIdx.x;
        if (e < P * 3) {
            const int p = e / 3, c = e - p * 3;
            __builtin_nontemporal_store(meshf[e], &out[p * 227 + 224 + c]);
        }
    }
}

extern "C" void kernel_launch(void* const* d_in, const int* in_sizes, int n_in,
                              void* d_out, int out_size, void* d_ws, size_t ws_size,
                              hipStream_t stream) {
    const float* f1     = (const float*)d_in[1];
    const float* f2     = (const float*)d_in[2];
    const float* f3     = (const float*)d_in[3];
    const float* coords = (const float*)d_in[5];
    const float* meshf  = (const float*)d_in[6];
    float* out = (float*)d_out;

    const int B = in_sizes[1] / (64 * 64 * 64 * 32);
    const int N = in_sizes[5] / (B * 3);
    const int P = B * N;

    const int NBINS = 8192;                 // 2 batches x 16^3 cells
    const size_t ws_need = (size_t)NBINS * 4 + (size_t)P * 4 + (size_t)P * 12;
    unsigned* bins  = (unsigned*)d_ws;
    unsigned* perm  = bins + NBINS;
    float*    csort = (float*)(perm + P);
    const bool do_sort = (d_ws != nullptr) && (ws_size >= ws_need);

    if (do_sort) {
        hipMemsetAsync(bins, 0, NBINS * 4, stream);
        const int nbp = (P + 255) / 256;
        hist_kernel<<<dim3(nbp), dim3(256), 0, stream>>>(coords, bins, N, P);
        scan_kernel<<<dim3(1), dim3(1024), 0, stream>>>(bins);
        scatter_kernel<<<dim3(nbp), dim3(256), 0, stream>>>(coords, bins, perm,
                                                            csort, N, P);
    }

    const int nb1 = (P + 31) / 32;          // 32 points/block (8 pts/wave)
    const int nb2 = (P + 15) / 16;          // 16 points/block
    const int nb3 = (P + 7) / 8;            //  8 points/block
    const int nbm = (P * 3 + 255) / 256;    // mesh copy blocks
    const int grid = nb1 + nb2 + nb3 + nbm;

    trilerp_kernel<<<dim3(grid), dim3(256), 0, stream>>>(
        f1, f2, f3, coords, meshf,
        do_sort ? csort : nullptr, do_sort ? perm : nullptr,
        out, N, P, nb1, nb2, nb3);
}

// Round 7
// 228.670 us; speedup vs baseline: 1.1192x; 1.0180x over previous
//
#include <hip/hip_runtime.h>

// Trilerp of 3 feature levels + mesh concat, with spatial counting-sort and
// BUCKET-BLOCK LDS REUSE for lvl2/lvl3.
//
// Evidence so far: time (~83 us) is invariant under scheduling (r0/1/3),
// cache locality (r5: FETCH 127->40 MB, no time change), and occupancy
// (r4->r5). Remaining invariant: vector-memory instruction/sector count
// (700k gather instrs / 11.2M sectors + 350k store instrs / 5.6M sectors).
// Theory: per-CU TA/TCP request throughput is the wall. This revision cuts
// gather requests with compute-level reuse: one block per spatial bucket
// (16^3 cell), features staged ONCE in LDS, all ~24 bucket points read LDS.
//   lvl3 (16^3 x128ch): bucket = 1 cell -> 2^3 cells x 512B = 4 KB tile, ~24x
//   lvl2 (32^3 x 64ch): bucket = 2^3 cells -> 3^3 cells x 256B = 6.9 KB, ~7x
//   lvl1 (64^3 x 32ch): only 1.5x shareable -> keep direct asm gathers.
// Sort kernels (hist/scan/scatter->perm+csort) as round 5; bins[] after
// scatter holds bucket ENDS (start = bins[bid-1] or 0).
// (Round 6 submission of this source died to a container-provisioning
// failure before any dispatch ran; resubmitted unchanged.)
// Output layout: [B,N,227] = [32 | 64 | 128 | 3 mesh].

typedef float floatx4 __attribute__((ext_vector_type(4)));

#define NBINS 8192   // 2 batches x 16^3 cells

__device__ __forceinline__ int point_batch(int p, int N) {
    int b = 0;
    while (p >= N) { p -= N; ++b; }   // B is tiny (2)
    return b;
}

__device__ __forceinline__ int bucket_of(const float* __restrict__ coords,
                                         int p, int N) {
    const float cx = coords[p * 3 + 0];
    const float cy = coords[p * 3 + 1];
    const float cz = coords[p * 3 + 2];
    int bx = (int)(cx * 16.0f); bx = bx < 0 ? 0 : (bx > 15 ? 15 : bx);
    int by = (int)(cy * 16.0f); by = by < 0 ? 0 : (by > 15 ? 15 : by);
    int bz = (int)(cz * 16.0f); bz = bz < 0 ? 0 : (bz > 15 ? 15 : bz);
    // z fastest: matches feature memory layout (z,c contiguous).
    return ((point_batch(p, N) * 16 + bx) * 16 + by) * 16 + bz;
}

__global__ __launch_bounds__(256) void hist_kernel(
    const float* __restrict__ coords, unsigned* __restrict__ bins,
    int N, int P)
{
    const int p = blockIdx.x * 256 + (int)threadIdx.x;
    if (p < P) atomicAdd(&bins[bucket_of(coords, p, N)], 1u);
}

// Exclusive scan of 8192 bins; 1024 threads x 8 bins each.
__global__ __launch_bounds__(1024) void scan_kernel(unsigned* __restrict__ bins)
{
    __shared__ unsigned part[1024];
    const int t = threadIdx.x;
    unsigned loc[8];
    unsigned s = 0;
    for (int i = 0; i < 8; ++i) {
        unsigned v = bins[t * 8 + i];
        loc[i] = s;           // thread-local exclusive prefix
        s += v;
    }
    part[t] = s;
    __syncthreads();
    for (int off = 1; off < 1024; off <<= 1) {
        unsigned v = (t >= off) ? part[t - off] : 0u;
        __syncthreads();
        part[t] += v;
        __syncthreads();
    }
    const unsigned base = (t == 0) ? 0u : part[t - 1];
    for (int i = 0; i < 8; ++i) bins[t * 8 + i] = base + loc[i];
}

__global__ __launch_bounds__(256) void scatter_kernel(
    const float* __restrict__ coords, unsigned* __restrict__ bins,
    unsigned* __restrict__ perm, float* __restrict__ csort,
    int N, int P)
{
    const int p = blockIdx.x * 256 + (int)threadIdx.x;
    if (p < P) {
        const unsigned pos = atomicAdd(&bins[bucket_of(coords, p, N)], 1u);
        perm[pos] = (unsigned)p;
        csort[pos * 3 + 0] = coords[p * 3 + 0];
        csort[pos * 3 + 1] = coords[p * 3 + 1];
        csort[pos * 3 + 2] = coords[p * 3 + 2];
    }
}

// Bijective chunked XCD swizzle within a segment of S blocks (m204 variant).
__device__ __forceinline__ int seg_swz(int lo, int S) {
    const int q = S >> 3, r = S & 7;
    const int xcd = lo & 7, j = lo >> 3;
    return (xcd < r ? xcd * (q + 1) : r * (q + 1) + (xcd - r) * q) + j;
}

// ---------------- bucket-block LDS path (lvl2 / lvl3) ----------------
// D: grid dim; C: channels; OCB: out channel base; NC: tile cells per axis.
template<int D, int C, int OCB, int NC>
__device__ __forceinline__ void do_bucket(const float* __restrict__ fbase,
                                          const unsigned* __restrict__ bins,
                                          const float* __restrict__ csort,
                                          const unsigned* __restrict__ perm,
                                          float* __restrict__ out,
                                          int bid, float* __restrict__ lds)
{
    constexpr int LPP = C / 4;         // lanes per point
    constexpr int SB  = D / 16;        // level cells per bucket step (1 or 2)
    const int tid = threadIdx.x;

    const int s = (bid ? (int)bins[bid - 1] : 0);
    const int e = (int)bins[bid];
    if (s >= e) return;                // uniform: whole block exits, no sync yet

    const int b  = bid >> 12;
    const int bx = (bid >> 8) & 15;
    const int by = (bid >> 4) & 15;
    const int bz = bid & 15;
    const int xt = min(bx * SB, D - NC);
    const int yt = min(by * SB, D - NC);
    const int zt = min(bz * SB, D - NC);

    // Cooperative tile load: NC^3 cells x C floats, 16B chunks, coalesced.
    constexpr int CHPC   = C / 4;                 // 16B chunks per cell
    constexpr int CHUNKS = NC * NC * NC * CHPC;
    for (int t = tid; t < CHUNKS; t += 256) {
        const int cell = t / CHPC;                // CHPC is a power of 2
        const int w    = t & (CHPC - 1);
        const int dx = cell / (NC * NC);
        const int rem = cell - dx * NC * NC;
        const int dy = rem / NC;
        const int dz = rem - dy * NC;
        const int gx = xt + dx, gy = yt + dy, gz = zt + dz;
        const int goff = (((b * D + gx) * D + gy) * D + gz) * C + w * 4;
        *(floatx4*)(lds + cell * C + w * 4) = *(const floatx4*)(fbase + goff);
    }
    __syncthreads();

    constexpr int PPP = 256 / LPP;     // points per pass
    const int lp = tid / LPP;
    const int c4 = tid & (LPP - 1);
    const floatx4* T = (const floatx4*)lds;

    const float scale = (float)D;
    const float hi    = (float)((double)D - 1.01);

    for (int base = s; base < e; base += PPP) {
        const int slot = base + lp;
        if (slot >= e) continue;       // no sync below: safe divergence

        const float cx = csort[slot * 3 + 0];
        const float cy = csort[slot * 3 + 1];
        const float cz = csort[slot * 3 + 2];

        const float ix = fminf(fmaxf(cx * scale, 0.01f), hi);
        const float iy = fminf(fmaxf(cy * scale, 0.01f), hi);
        const float iz = fminf(fmaxf(cz * scale, 0.01f), hi);

        const float x1f = floorf(ix), x2f = ceilf(ix);
        const float y1f = floorf(iy), y2f = ceilf(iy);
        const float z1f = floorf(iz), z2f = ceilf(iz);
        const int lx1 = (int)x1f - xt, lx2 = (int)x2f - xt;
        const int ly1 = (int)y1f - yt, ly2 = (int)y2f - yt;
        const int lz1 = (int)z1f - zt, lz2 = (int)z2f - zt;

        const float wx = ix - x1f, wx2 = x2f - ix;
        const float wy = iy - y1f, wy2 = y2f - iy;
        const float wz = iz - z1f, wz2 = z2f - iz;

        #define LT(LX, LY, LZ) T[((((LX) * NC + (LY)) * NC + (LZ)) * LPP) + c4]
        const floatx4 v111 = LT(lx1, ly1, lz1);
        const floatx4 v211 = LT(lx2, ly1, lz1);
        const floatx4 v121 = LT(lx1, ly2, lz1);
        const floatx4 v221 = LT(lx2, ly2, lz1);
        const floatx4 v112 = LT(lx1, ly1, lz2);
        const floatx4 v212 = LT(lx2, ly1, lz2);
        const floatx4 v122 = LT(lx1, ly2, lz2);
        const floatx4 v222 = LT(lx2, ly2, lz2);
        #undef LT

        const floatx4 lx1a = v211 * wx + v111 * wx2;
        const floatx4 lx2a = v221 * wx + v121 * wx2;
        const floatx4 ly1v = lx2a * wy + lx1a * wy2;
        const floatx4 lx1b = v212 * wx + v112 * wx2;
        const floatx4 lx2b = v222 * wx + v122 * wx2;
        const floatx4 ly2v = lx2b * wy + lx1b * wy2;
        const floatx4 r    = ly2v * wz + ly1v * wz2;

        float* o = out + (int)perm[slot] * 227 + OCB + c4 * 4;
        __builtin_nontemporal_store(r.x, o + 0);
        __builtin_nontemporal_store(r.y, o + 1);
        __builtin_nontemporal_store(r.z, o + 2);
        __builtin_nontemporal_store(r.w, o + 3);
    }
}

// ---------------- direct-gather path (lvl1, and fallback) ----------------
template<int D, int LPP, int OCB>
__device__ __forceinline__ void do_level(const float* __restrict__ fbase,
                                         const float* __restrict__ coords,
                                         const float* __restrict__ csort,
                                         const unsigned* __restrict__ perm,
                                         float* __restrict__ out,
                                         int sBase, int N, int P)
{
    const int tid  = threadIdx.x;
    const int lane = tid & 63;
    const int wv   = tid >> 6;
    const int slot = sBase + wv * (64 / LPP) + (lane / LPP);
    const int c4   = lane & (LPP - 1);
    if (slot >= P) return;
    const int p = perm ? (int)perm[slot] : slot;   // output row (original order)

    const float* cp = csort ? (csort + slot * 3) : (coords + p * 3);
    const float cx = cp[0];
    const float cy = cp[1];
    const float cz = cp[2];

    const float scale = (float)D;
    const float hi    = (float)((double)D - 1.01);

    const float ix = fminf(fmaxf(cx * scale, 0.01f), hi);
    const float iy = fminf(fmaxf(cy * scale, 0.01f), hi);
    const float iz = fminf(fmaxf(cz * scale, 0.01f), hi);

    const float x1f = floorf(ix), x2f = ceilf(ix);
    const float y1f = floorf(iy), y2f = ceilf(iy);
    const float z1f = floorf(iz), z2f = ceilf(iz);
    const int x1 = (int)x1f, x2 = (int)x2f;
    const int y1 = (int)y1f, y2 = (int)y2f;
    const int z1 = (int)z1f, z2 = (int)z2f;

    const float wx = ix - x1f, wx2 = x2f - ix;
    const float wy = iy - y1f, wy2 = y2f - iy;
    const float wz = iz - z1f, wz2 = z2f - iz;

    const unsigned baseB = (unsigned)point_batch(p, N) * (unsigned)(D * D * D * LPP * 16)
                         + (unsigned)c4 * 16u;
    #define OFFB(X, Y, Z) (baseB + (unsigned)((((X) * D + (Y)) * D + (Z)) * LPP) * 16u)

    floatx4 v111, v211, v121, v221, v112, v212, v122, v222;
    asm volatile("global_load_dwordx4 %0, %1, %2"
                 : "=v"(v111) : "v"(OFFB(x1, y1, z1)), "s"(fbase));
    asm volatile("global_load_dwordx4 %0, %1, %2"
                 : "=v"(v211) : "v"(OFFB(x2, y1, z1)), "s"(fbase));
    asm volatile("global_load_dwordx4 %0, %1, %2"
                 : "=v"(v121) : "v"(OFFB(x1, y2, z1)), "s"(fbase));
    asm volatile("global_load_dwordx4 %0, %1, %2"
                 : "=v"(v221) : "v"(OFFB(x2, y2, z1)), "s"(fbase));
    asm volatile("global_load_dwordx4 %0, %1, %2"
                 : "=v"(v112) : "v"(OFFB(x1, y1, z2)), "s"(fbase));
    asm volatile("global_load_dwordx4 %0, %1, %2"
                 : "=v"(v212) : "v"(OFFB(x2, y1, z2)), "s"(fbase));
    asm volatile("global_load_dwordx4 %0, %1, %2"
                 : "=v"(v122) : "v"(OFFB(x1, y2, z2)), "s"(fbase));
    asm volatile("global_load_dwordx4 %0, %1, %2"
                 : "=v"(v222) : "v"(OFFB(x2, y2, z2)), "s"(fbase));
    #undef OFFB

    asm volatile("s_waitcnt vmcnt(0)");
    __builtin_amdgcn_sched_barrier(0);

    const floatx4 lx1a = v211 * wx + v111 * wx2;
    const floatx4 lx2a = v221 * wx + v121 * wx2;
    const floatx4 ly1  = lx2a * wy + lx1a * wy2;
    const floatx4 lx1b = v212 * wx + v112 * wx2;
    const floatx4 lx2b = v222 * wx + v122 * wx2;
    const floatx4 ly2  = lx2b * wy + lx1b * wy2;
    const floatx4 r    = ly2  * wz + ly1  * wz2;

    float* o = out + p * 227 + OCB + c4 * 4;
    __builtin_nontemporal_store(r.x, o + 0);
    __builtin_nontemporal_store(r.y, o + 1);
    __builtin_nontemporal_store(r.z, o + 2);
    __builtin_nontemporal_store(r.w, o + 3);
}

// Main kernel (sorted path): [lvl3 buckets | lvl2 buckets | lvl1 | mesh]
__global__ __launch_bounds__(256, 8) void trilerp_kernel(
    const float* __restrict__ f1,      // [B,64,64,64,32]
    const float* __restrict__ f2,      // [B,32,32,32,64]
    const float* __restrict__ f3,      // [B,16,16,16,128]
    const float* __restrict__ coords,  // [B,N,3]
    const float* __restrict__ meshf,   // [B,N,3]
    const float* __restrict__ csort,   // [P,3] sorted coords
    const unsigned* __restrict__ perm, // [P] sorted-slot -> point
    const unsigned* __restrict__ bins, // [NBINS] bucket ENDS after scatter
    float* __restrict__ out,           // [B,N,227]
    int N, int P, int nb1)
{
    __shared__ float tile[3 * 3 * 3 * 64];   // 6912 B, max of both tiles
    const int orig = (int)blockIdx.x;

    if (orig < NBINS) {
        const int bid = seg_swz(orig, NBINS);
        do_bucket<16, 128, 96, 2>(f3, bins, csort, perm, out, bid, tile);
    } else if (orig < 2 * NBINS) {
        const int bid = seg_swz(orig - NBINS, NBINS);
        do_bucket<32, 64, 32, 3>(f2, bins, csort, perm, out, bid, tile);
    } else if (orig < 2 * NBINS + nb1) {
        const int blk = seg_swz(orig - 2 * NBINS, nb1);
        do_level<64, 8, 0>(f1, coords, csort, perm, out, blk * 32, N, P);
    } else {
        const int e = (orig - 2 * NBINS - nb1) * 256 + (int)threadIdx.x;
        if (e < P * 3) {
            const int p = e / 3, c = e - p * 3;
            __builtin_nontemporal_store(meshf[e], &out[p * 227 + 224 + c]);
        }
    }
}

// Fallback (no workspace): round-5 structure, identity order.
__global__ __launch_bounds__(256, 8) void trilerp_fallback_kernel(
    const float* __restrict__ f1, const float* __restrict__ f2,
    const float* __restrict__ f3, const float* __restrict__ coords,
    const float* __restrict__ meshf, float* __restrict__ out,
    int N, int P, int nb1, int nb2, int nb3)
{
    const int orig = (int)blockIdx.x;
    if (orig < nb1) {
        do_level<64, 8, 0>(f1, coords, nullptr, nullptr, out, orig * 32, N, P);
    } else if (orig < nb1 + nb2) {
        do_level<32, 16, 32>(f2, coords, nullptr, nullptr, out, (orig - nb1) * 16, N, P);
    } else if (orig < nb1 + nb2 + nb3) {
        do_level<16, 32, 96>(f3, coords, nullptr, nullptr, out, (orig - nb1 - nb2) * 8, N, P);
    } else {
        const int e = (orig - nb1 - nb2 - nb3) * 256 + (int)threadIdx.x;
        if (e < P * 3) {
            const int p = e / 3, c = e - p * 3;
            __builtin_nontemporal_store(meshf[e], &out[p * 227 + 224 + c]);
        }
    }
}

extern "C" void kernel_launch(void* const* d_in, const int* in_sizes, int n_in,
                              void* d_out, int out_size, void* d_ws, size_t ws_size,
                              hipStream_t stream) {
    const float* f1     = (const float*)d_in[1];
    const float* f2     = (const float*)d_in[2];
    const float* f3     = (const float*)d_in[3];
    const float* coords = (const float*)d_in[5];
    const float* meshf  = (const float*)d_in[6];
    float* out = (float*)d_out;

    const int B = in_sizes[1] / (64 * 64 * 64 * 32);
    const int N = in_sizes[5] / (B * 3);
    const int P = B * N;

    const size_t ws_need = (size_t)NBINS * 4 + (size_t)P * 4 + (size_t)P * 12;
    unsigned* bins  = (unsigned*)d_ws;
    unsigned* perm  = bins + NBINS;
    float*    csort = (float*)(perm + P);
    const bool do_sort = (d_ws != nullptr) && (ws_size >= ws_need);

    const int nb1 = (P + 31) / 32;          // lvl1: 32 points/block
    const int nbm = (P * 3 + 255) / 256;    // mesh copy blocks

    if (do_sort) {
        hipMemsetAsync(bins, 0, NBINS * 4, stream);
        const int nbp = (P + 255) / 256;
        hist_kernel<<<dim3(nbp), dim3(256), 0, stream>>>(coords, bins, N, P);
        scan_kernel<<<dim3(1), dim3(1024), 0, stream>>>(bins);
        scatter_kernel<<<dim3(nbp), dim3(256), 0, stream>>>(coords, bins, perm,
                                                            csort, N, P);
        const int grid = 2 * NBINS + nb1 + nbm;
        trilerp_kernel<<<dim3(grid), dim3(256), 0, stream>>>(
            f1, f2, f3, coords, meshf, csort, perm, bins, out, N, P, nb1);
    } else {
        const int nb2 = (P + 15) / 16;
        const int nb3 = (P + 7) / 8;
        const int grid = nb1 + nb2 + nb3 + nbm;
        trilerp_fallback_kernel<<<dim3(grid), dim3(256), 0, stream>>>(
            f1, f2, f3, coords, meshf, out, N, P, nb1, nb2, nb3);
    }
}

// Round 8
// 214.603 us; speedup vs baseline: 1.1925x; 1.0655x over previous
//
#include <hip/hip_runtime.h>

// FUSED trilerp: one kernel, one block per 4 consecutive points, full-row
// assembly in LDS, coalesced full-sector output stores.
//
// Seven rounds of evidence: dispatch time (~80 us) is invariant under
// instruction scheduling / MLP (r0/r1/r3), cache locality (r5: FETCH
// 127->40 MB, no change), occupancy (46-76%), and load-request count
// (r7: ~5x cut via LDS bucket tiles, no change). The ONLY untouched path
// was the output: every round wrote each 908-B row in 4 disjoint partial-
// sector bursts (32|64|128|3 ch) from different waves -> WRITE_SIZE pinned
// at ~100 MB and FETCH's residual 39 MB matches the RMW read traffic of
// ~6 partial 64B sectors/row. Theory: the wall is the partial-sector
// write/RMW drain. This kernel:
//   - block = 4 consecutive points; 56 lanes/point (8 lvl1 + 16 lvl2 +
//     32 lvl3) in a SINGLE branchless uniform gather path (level params
//     selected per-lane -> no divergence);
//   - rows assembled in LDS (scalar writes, no alignment constraint);
//   - block's 4 rows = 3632 B = 227 float4, 16B-aligned, stored
//     cooperatively -> full sectors, zero RMW except block edges.
// No sort, no workspace (r5/r7: sorting never bought time, cost ~19 us).
// Output layout: [B,N,227] = [32 | 64 | 128 | 3 mesh].

typedef float floatx4 __attribute__((ext_vector_type(4)));

#define G 4          // points per block
#define THREADS 256

__global__ __launch_bounds__(THREADS, 8) void trilerp_fused_kernel(
    const float* __restrict__ f1,      // [B,64,64,64,32]
    const float* __restrict__ f2,      // [B,32,32,32,64]
    const float* __restrict__ f3,      // [B,16,16,16,128]
    const float* __restrict__ coords,  // [B,N,3]
    const float* __restrict__ meshf,   // [B,N,3]
    float* __restrict__ out,           // [B,N,227]
    int N, int P)
{
    __shared__ float rowbuf[G * 227];  // 3632 B
    const int tid = (int)threadIdx.x;
    const int p0  = (int)blockIdx.x * G;

    if (tid < G * 56) {
        const int pt   = tid / 56;
        const int role = tid - pt * 56;
        const int p    = p0 + pt;
        if (p < P) {
            // Branchless per-lane level parameters (no wave divergence:
            // every lane runs the identical instruction stream).
            const int lvl = (role < 8) ? 0 : ((role < 24) ? 1 : 2);
            const int D   = 64 >> lvl;                   // 64, 32, 16
            const int C   = 32 << lvl;                   // 32, 64, 128
            const int c4  = role - ((lvl == 0) ? 0 : ((lvl == 1) ? 8 : 24));
            const int ocb = (lvl == 0) ? 0 : ((lvl == 1) ? 32 : 96);
            const float* fb = (lvl == 0) ? f1 : ((lvl == 1) ? f2 : f3);

            const int b = (p >= N) ? 1 : 0;

            const float cx = coords[p * 3 + 0];
            const float cy = coords[p * 3 + 1];
            const float cz = coords[p * 3 + 2];

            const float scale = (float)D;                    // 0.5^pow * 128
            const float hi    = (float)((double)D - 1.01);   // matches Python

            const float ix = fminf(fmaxf(cx * scale, 0.01f), hi);
            const float iy = fminf(fmaxf(cy * scale, 0.01f), hi);
            const float iz = fminf(fmaxf(cz * scale, 0.01f), hi);

            const float x1f = floorf(ix), x2f = ceilf(ix);
            const float y1f = floorf(iy), y2f = ceilf(iy);
            const float z1f = floorf(iz), z2f = ceilf(iz);
            const int x1 = (int)x1f, x2 = (int)x2f;
            const int y1 = (int)y1f, y2 = (int)y2f;
            const int z1 = (int)z1f, z2 = (int)z2f;

            // Reference weight convention: wx multiplies the x2 (ceil) sample.
            const float wx = ix - x1f, wx2 = x2f - ix;
            const float wy = iy - y1f, wy2 = y2f - iy;
            const float wz = iz - z1f, wz2 = z2f - iz;

            #define OFF(X, Y, Z) ((((((b) * D + (X)) * D + (Y)) * D + (Z)) * C) + c4 * 4)
            const floatx4 v111 = *(const floatx4*)(fb + OFF(x1, y1, z1));
            const floatx4 v211 = *(const floatx4*)(fb + OFF(x2, y1, z1));
            const floatx4 v121 = *(const floatx4*)(fb + OFF(x1, y2, z1));
            const floatx4 v221 = *(const floatx4*)(fb + OFF(x2, y2, z1));
            const floatx4 v112 = *(const floatx4*)(fb + OFF(x1, y1, z2));
            const floatx4 v212 = *(const floatx4*)(fb + OFF(x2, y1, z2));
            const floatx4 v122 = *(const floatx4*)(fb + OFF(x1, y2, z2));
            const floatx4 v222 = *(const floatx4*)(fb + OFF(x2, y2, z2));
            #undef OFF

            const floatx4 lx1a = v211 * wx + v111 * wx2;
            const floatx4 lx2a = v221 * wx + v121 * wx2;
            const floatx4 ly1v = lx2a * wy + lx1a * wy2;
            const floatx4 lx1b = v212 * wx + v112 * wx2;
            const floatx4 lx2b = v222 * wx + v122 * wx2;
            const floatx4 ly2v = lx2b * wy + lx1b * wy2;
            const floatx4 r    = ly2v * wz + ly1v * wz2;

            // Scalar LDS writes: 227-float row stride has no 16B-alignment
            // guarantee for vector ds_write; scalar b32 needs none.
            float* rb = rowbuf + pt * 227 + ocb + c4 * 4;
            rb[0] = r.x; rb[1] = r.y; rb[2] = r.z; rb[3] = r.w;
        }
    } else if (tid < G * 56 + G * 3) {
        // mesh passthrough into the row tail
        const int i  = tid - G * 56;
        const int pt = i / 3, c = i - pt * 3;
        const int p  = p0 + pt;
        if (p < P) rowbuf[pt * 227 + 224 + c] = meshf[p * 3 + c];
    }

    __syncthreads();

    // Cooperative store of the block's contiguous output chunk.
    const int nrow = min(G, P - p0);
    if (nrow == G) {
        // 4 rows x 227 floats = 227 float4, chunk base 16B-aligned
        // (4*908 = 3632 = 227*16). Full 64B sectors except chunk edges,
        // which adjacent blocks' chunks complete in L2.
        if (tid < 227) {
            const floatx4 v = *(const floatx4*)(rowbuf + tid * 4);
            __builtin_nontemporal_store(v, (floatx4*)(out + (size_t)p0 * 227) + tid);
        }
    } else if (nrow > 0) {
        // tail block: scalar coalesced stores
        for (int i = tid; i < nrow * 227; i += THREADS)
            out[(size_t)p0 * 227 + i] = rowbuf[i];
    }
}

extern "C" void kernel_launch(void* const* d_in, const int* in_sizes, int n_in,
                              void* d_out, int out_size, void* d_ws, size_t ws_size,
                              hipStream_t stream) {
    const float* f1     = (const float*)d_in[1];
    const float* f2     = (const float*)d_in[2];
    const float* f3     = (const float*)d_in[3];
    const float* coords = (const float*)d_in[5];
    const float* meshf  = (const float*)d_in[6];
    float* out = (float*)d_out;

    const int B = in_sizes[1] / (64 * 64 * 64 * 32);
    const int N = in_sizes[5] / (B * 3);
    const int P = B * N;

    const int grid = (P + G - 1) / G;
    trilerp_fused_kernel<<<dim3(grid), dim3(THREADS), 0, stream>>>(
        f1, f2, f3, coords, meshf, out, N, P);
}